// Round 11
// baseline (439.193 us; speedup 1.0000x reference)
//
#include <hip/hip_runtime.h>
#include <math.h>

#define NPTS 4096
#define BLK 128
#define V 64
#define NPROJ 256
#define NBATCH 32

// R11: zero-LDS bitonic sort. One wave per array (V=64 regs/thread,
// A layout: idx = t*64 + r, t=lane idx[11:6], r=reg idx[5:0]).
// All cross-thread exchanges are intra-wave lane exchanges via __shfl_xor
// (DPP for masks 1,2,3,7,15; ds_bpermute for 4..63) — no LDS write->read
// round-trips, no lgkmcnt(0) drains, no barriers inside the sort.
// R8-R10 post-mortems: the 9 LDS trips cost little issue time but ~80%
// stall time (write->all-lanes-dependency->read). Shuffles have the same
// DS-pipe throughput but are independent single instructions.
// Network = R8's validated normalized bitonic (absmax 0): merges 2..64
// in-reg; merges 128..4096 = rev_shfl<m/64-1> + stage_shfl chain + in-reg
// tail. Block = 2 waves: wave0 sorts x, wave1 sorts y; wave1 publishes to
// a 16 KB LDS buffer; one barrier; wave0 diffs and atomically accumulates.

__device__ __forceinline__ void cmpex_asc(float& a, float& b) {
    const float lo = fminf(a, b), hi = fmaxf(a, b);
    a = lo; b = hi;
}

template<int JB, int JL>
__device__ __forceinline__ void stages(float* v) {
#pragma unroll
    for (int r = 0; r < V; ++r)
        if ((r & JB) == 0) cmpex_asc(v[r], v[r | JB]);
    if constexpr (JB > JL) stages<(JB >> 1), JL>(v);
}

template<int MASK>
__device__ __forceinline__ void rev_inreg(float* v) {
    constexpr int S = (MASK + 1) >> 1;
#pragma unroll
    for (int r = 0; r < V; ++r) {
        if ((r & S) == 0) {
            const float a = v[r], b = v[r ^ MASK];
            v[r] = fminf(a, b);
            v[r ^ MASK] = fmaxf(a, b);
        }
    }
}

// Merge-(128*XM...) reversal across lane pair t^XM, registers reversed
// (r <-> 63-r). hi = this lane's keep side = (t & ((XM+1)>>1)) != 0.
template<int XM>
__device__ __forceinline__ void rev_shfl(float* v, bool hi) {
#pragma unroll
    for (int r = 0; r < 32; ++r) {
        const float pa = __shfl_xor(v[63 - r], XM, 64);
        const float pb = __shfl_xor(v[r], XM, 64);
        v[r]      = hi ? fmaxf(v[r], pa)      : fminf(v[r], pa);
        v[63 - r] = hi ? fmaxf(v[63 - r], pb) : fminf(v[63 - r], pb);
    }
}
// Cleaner stage j = XM*64: same-register exchange across lane t^XM.
// hi = (t & XM) != 0.
template<int XM>
__device__ __forceinline__ void stage_shfl(float* v, bool hi) {
#pragma unroll
    for (int r = 0; r < V; ++r) {
        const float q = __shfl_xor(v[r], XM, 64);
        v[r] = hi ? fmaxf(v[r], q) : fminf(v[r], q);
    }
}

__device__ __forceinline__ void load_project(const float* base, float* v,
                                             float p0, float p1, float p2) {
    const float4* b4 = (const float4*)base;
#pragma unroll
    for (int g = 0; g < 16; ++g) {
        float4 a = b4[g * 3 + 0], c = b4[g * 3 + 1], d = b4[g * 3 + 2];
        v[4*g+0] = a.x * p0 + a.y * p1 + a.z * p2;
        v[4*g+1] = a.w * p0 + c.x * p1 + c.y * p2;
        v[4*g+2] = c.z * p0 + c.w * p1 + d.x * p2;
        v[4*g+3] = d.y * p0 + d.z * p1 + d.w * p2;
    }
}

// Full ascending in-register sort of 4096 floats (one wave).
__device__ __forceinline__ void sort4096_reg(float* v, int t) {
    const bool h1  = (t & 1) != 0;
    const bool h2  = (t & 2) != 0;
    const bool h4  = (t & 4) != 0;
    const bool h8  = (t & 8) != 0;
    const bool h16 = (t & 16) != 0;
    const bool h32 = (t & 32) != 0;

    // merges 2..64: fully in-register
    rev_inreg<1>(v);
    rev_inreg<3>(v);  stages<1, 1>(v);
    rev_inreg<7>(v);  stages<2, 1>(v);
    rev_inreg<15>(v); stages<4, 1>(v);
    rev_inreg<31>(v); stages<8, 1>(v);
    rev_inreg<63>(v); stages<16, 1>(v);

    // merge 128
    rev_shfl<1>(v, h1);
    stages<32, 1>(v);
    // merge 256
    rev_shfl<3>(v, h2);
    stage_shfl<2>(v, h2); stage_shfl<1>(v, h1);
    stages<32, 1>(v);
    // merge 512
    rev_shfl<7>(v, h4);
    stage_shfl<4>(v, h4); stage_shfl<2>(v, h2); stage_shfl<1>(v, h1);
    stages<32, 1>(v);
    // merge 1024
    rev_shfl<15>(v, h8);
    stage_shfl<8>(v, h8); stage_shfl<4>(v, h4);
    stage_shfl<2>(v, h2); stage_shfl<1>(v, h1);
    stages<32, 1>(v);
    // merge 2048
    rev_shfl<31>(v, h16);
    stage_shfl<16>(v, h16); stage_shfl<8>(v, h8); stage_shfl<4>(v, h4);
    stage_shfl<2>(v, h2); stage_shfl<1>(v, h1);
    stages<32, 1>(v);
    // merge 4096
    rev_shfl<63>(v, h32);
    stage_shfl<32>(v, h32); stage_shfl<16>(v, h16); stage_shfl<8>(v, h8);
    stage_shfl<4>(v, h4); stage_shfl<2>(v, h2); stage_shfl<1>(v, h1);
    stages<32, 1>(v);
}

__global__ __launch_bounds__(BLK, 4) void swd_kernel(
    const float* __restrict__ x, const float* __restrict__ y,
    const float* __restrict__ theta, const float* __restrict__ rot,
    float* __restrict__ per_batch) {
    __shared__ float buf[NPTS];   // y publish buffer (only LDS use)

    const int t = threadIdx.x & 63;        // wave lane
    const int w = threadIdx.x >> 6;        // 0: x-wave, 1: y-wave
    const int p = blockIdx.x;
    const int b = blockIdx.y;

    const float t0 = theta[p * 3 + 0], t1 = theta[p * 3 + 1], t2 = theta[p * 3 + 2];
    const float* R = rot + b * 9;
    const float p0 = t0 * R[0] + t1 * R[3] + t2 * R[6];
    const float p1 = t0 * R[1] + t1 * R[4] + t2 * R[7];
    const float p2 = t0 * R[2] + t1 * R[5] + t2 * R[8];

    const float* src = w ? y : x;

    float v[V];
    load_project(src + (size_t)b * NPTS * 3 + (size_t)t * V * 3, v, p0, p1, p2);
    sort4096_reg(v, t);

    // Wave 1 publishes sorted y (natural A layout, b128, bank-even).
    if (w == 1) {
        float4* s4 = (float4*)buf;
#pragma unroll
        for (int c = 0; c < 16; ++c)
            s4[t * 16 + c] = make_float4(v[4*c], v[4*c+1], v[4*c+2], v[4*c+3]);
    }
    __syncthreads();

    if (w == 0) {
        const float4* s4 = (const float4*)buf;
        float s = 0.0f;
#pragma unroll
        for (int c = 0; c < 16; ++c) {
            const float4 f = s4[t * 16 + c];
            float d;
            d = v[4*c+0] - f.x; s += d * d;
            d = v[4*c+1] - f.y; s += d * d;
            d = v[4*c+2] - f.z; s += d * d;
            d = v[4*c+3] - f.w; s += d * d;
        }
        for (int off = 32; off > 0; off >>= 1) s += __shfl_down(s, off, 64);
        if (t == 0) atomicAdd(&per_batch[b], s);
    }
}

__global__ void finalize_kernel(const float* __restrict__ per_batch, float* __restrict__ out) {
    const int t = threadIdx.x;  // 64 threads
    float v = (t < NBATCH) ? sqrtf(per_batch[t] * (1.0f / (float)NPROJ)) : 0.0f;
    for (int off = 32; off > 0; off >>= 1) v += __shfl_down(v, off, 64);
    if (t == 0) out[0] = v * (1.0f / (float)NBATCH);
}

extern "C" void kernel_launch(void* const* d_in, const int* in_sizes, int n_in,
                              void* d_out, int out_size, void* d_ws, size_t ws_size,
                              hipStream_t stream) {
    const float* x = (const float*)d_in[0];
    const float* y = (const float*)d_in[1];
    const float* theta = (const float*)d_in[2];
    const float* rot = (const float*)d_in[3];
    float* per_batch = (float*)d_ws;
    float* out = (float*)d_out;

    hipMemsetAsync(per_batch, 0, NBATCH * sizeof(float), stream);

    dim3 grid(NPROJ, NBATCH);
    swd_kernel<<<grid, BLK, 0, stream>>>(x, y, theta, rot, per_batch);

    finalize_kernel<<<1, 64, 0, stream>>>(per_batch, out);
}

// Round 12
// 383.665 us; speedup vs baseline: 1.1447x; 1.1447x over previous
//
#include <hip/hip_runtime.h>
#include <math.h>

#define NPTS 4096
#define BLK 128
#define V 64
#define NPROJ 256
#define NBATCH 32

// R12 = R8's algorithm (two waves/block, private 16 KB buffers, barrier-free
// single-wave sorts, 9 LDS trips) with the code footprint halved: merges
// 128..4096 run in ONE '#pragma unroll 1' loop with runtime masks instead of
// six unrolled instantiations (~70 KB -> ~32 KB, at/below the 32 KB I$).
// Hypothesis: all R2-R11 variants (340-460 us) share an I$-streaming wall
// from fully-unrolled ~100 KB bodies.
// Layouts (element idx, 12 bits; T=wave-lane 6b, c=chunk 4b, l=comp 2b):
//   A: T=idx[11:6], c=idx[5:2]                (regs = idx[5:0])
//   B: T={idx[11:10],idx[5:2]}, c=idx[9:6]    (regs = {idx[9:6],idx[1:0]})
//   C: T=idx[9:4],  c={idx[11:10],idx[3:2]}   (regs = {idx[11:10],idx[3:0]})
// float4-slot placement: A/B: slot=(T<<4)|(c^(T&15)); C: slot=(T<<4)|(c^(T>>2&15)).
// All patterns bank-even and bijective (absmax 0 across R8-R10).
// Extra-stage reuse in the shared loop verified: per-merge B-stage sets are
// selected by uniform scalar conditions (no cross-merge-boundary cmpex).

__device__ __forceinline__ void cmpex_asc(float& a, float& b) {
    const float lo = fminf(a, b), hi = fmaxf(a, b);
    a = lo; b = hi;
}

template<int JB, int JL>
__device__ __forceinline__ void stages(float* v) {
#pragma unroll
    for (int r = 0; r < V; ++r)
        if ((r & JB) == 0) cmpex_asc(v[r], v[r | JB]);
    if constexpr (JB > JL) stages<(JB >> 1), JL>(v);
}

// Single cleaner stage (shared across merge iterations; layout-agnostic).
template<int JB>
__device__ __forceinline__ void stage1(float* v) {
#pragma unroll
    for (int r = 0; r < V; ++r)
        if ((r & JB) == 0) cmpex_asc(v[r], v[r | JB]);
}

template<int MASK>
__device__ __forceinline__ void rev_inreg(float* v) {
    constexpr int S = (MASK + 1) >> 1;
#pragma unroll
    for (int r = 0; r < V; ++r) {
        if ((r & S) == 0) {
            const float a = v[r], b = v[r ^ MASK];
            v[r] = fminf(a, b);
            v[r ^ MASK] = fmaxf(a, b);
        }
    }
}

// Reversal across lane pair t^xm (runtime mask), registers reversed.
__device__ __forceinline__ void rev_shfl_rt(float* v, int xm, bool hi) {
#pragma unroll
    for (int r = 0; r < 32; ++r) {
        const float pa = __shfl_xor(v[63 - r], xm, 64);
        const float pb = __shfl_xor(v[r], xm, 64);
        v[r]      = hi ? fmaxf(v[r], pa)      : fminf(v[r], pa);
        v[63 - r] = hi ? fmaxf(v[63 - r], pb) : fminf(v[63 - r], pb);
    }
}
// Cleaner stage across lane t^xm (runtime), same registers.
__device__ __forceinline__ void stage_shfl_rt(float* v, int xm, bool hi) {
#pragma unroll
    for (int r = 0; r < V; ++r) {
        const float q = __shfl_xor(v[r], xm, 64);
        v[r] = hi ? fmaxf(v[r], q) : fminf(v[r], q);
    }
}

// A->B and B->A scatter-write (same formula, symmetric).
__device__ __forceinline__ void write_AB(float* s, const float* v, int sAB, int t15) {
    float4* s4 = (float4*)s;
#pragma unroll
    for (int c = 0; c < 16; ++c)
        s4[sAB | (c << 4) | (t15 ^ c)] =
            make_float4(v[4*c], v[4*c+1], v[4*c+2], v[4*c+3]);
}
// Natural (own-slot) write, A/B-resident layout.
__device__ __forceinline__ void write_own(float* s, const float* v, int t, int t15) {
    float4* s4 = (float4*)s;
#pragma unroll
    for (int c = 0; c < 16; ++c)
        s4[(t << 4) | (c ^ t15)] =
            make_float4(v[4*c], v[4*c+1], v[4*c+2], v[4*c+3]);
}
// Own-slot read, valid for A- and B-resident phases.
__device__ __forceinline__ void read_own(const float* s, float* v, int t, int t15) {
    const float4* s4 = (const float4*)s;
#pragma unroll
    for (int c = 0; c < 16; ++c) {
        const float4 f = s4[(t << 4) | (c ^ t15)];
        v[4*c] = f.x; v[4*c+1] = f.y; v[4*c+2] = f.z; v[4*c+3] = f.w;
    }
}
// B-entry read fused with reversal, runtime masks PM/CM/KB/TB.
__device__ __forceinline__ void read_rev_rt(const float* s, float* v, int t, int t15,
                                            int PM, int CM, int KB, int TB) {
    const float4* s4 = (const float4*)s;
    const int pt = t ^ PM, pt15 = pt & 15;
    const int tb = t & TB;
#pragma unroll
    for (int c = 0; c < 16; ++c) {
        const float4 o = s4[(t << 4) | (c ^ t15)];
        const float4 q = s4[(pt << 4) | ((c ^ CM) ^ pt15)];
        const bool mx = ((c & KB) | tb) != 0;
        v[4*c+0] = mx ? fmaxf(o.x, q.w) : fminf(o.x, q.w);
        v[4*c+1] = mx ? fmaxf(o.y, q.z) : fminf(o.y, q.z);
        v[4*c+2] = mx ? fmaxf(o.z, q.y) : fminf(o.z, q.y);
        v[4*c+3] = mx ? fmaxf(o.w, q.x) : fminf(o.w, q.x);
    }
}
// A->C scatter-write.
__device__ __forceinline__ void write_AC(float* s, const float* v, int t15, int qAC) {
    float4* s4 = (float4*)s;
#pragma unroll
    for (int c = 0; c < 16; ++c)
        s4[(t15 << 6) | ((c >> 2) << 4) | (qAC ^ (c & 3))] =
            make_float4(v[4*c], v[4*c+1], v[4*c+2], v[4*c+3]);
}
// C-entry read fused with m4096 reversal (partner t^63, c^15, keep c&8).
__device__ __forceinline__ void read_rev_C(const float* s, float* v, int t, int th) {
    const float4* s4 = (const float4*)s;
    const int pt = t ^ 63, pth = th ^ 15;
#pragma unroll
    for (int c = 0; c < 16; ++c) {
        const float4 o = s4[(t << 4) | (c ^ th)];
        const float4 q = s4[(pt << 4) | ((c ^ 15) ^ pth)];
        const bool mx = (c & 8) != 0;
        v[4*c+0] = mx ? fmaxf(o.x, q.w) : fminf(o.x, q.w);
        v[4*c+1] = mx ? fmaxf(o.y, q.z) : fminf(o.y, q.z);
        v[4*c+2] = mx ? fmaxf(o.z, q.y) : fminf(o.z, q.y);
        v[4*c+3] = mx ? fmaxf(o.w, q.x) : fminf(o.w, q.x);
    }
}
// C->B scatter-write.
__device__ __forceinline__ void write_CB(float* s, const float* v, int sCB, int qCB) {
    float4* s4 = (float4*)s;
#pragma unroll
    for (int c = 0; c < 16; ++c)
        s4[((c >> 2) << 8) | sCB | ((c & 3) << 4) | (qCB ^ (c & 3))] =
            make_float4(v[4*c], v[4*c+1], v[4*c+2], v[4*c+3]);
}

__device__ __forceinline__ void load_project(const float* base, float* v,
                                             float p0, float p1, float p2) {
    const float4* b4 = (const float4*)base;
#pragma unroll
    for (int g = 0; g < 16; ++g) {
        float4 a = b4[g * 3 + 0], c = b4[g * 3 + 1], d = b4[g * 3 + 2];
        v[4*g+0] = a.x * p0 + a.y * p1 + a.z * p2;
        v[4*g+1] = a.w * p0 + c.x * p1 + c.y * p2;
        v[4*g+2] = c.z * p0 + c.w * p1 + d.x * p2;
        v[4*g+3] = d.y * p0 + d.z * p1 + d.w * p2;
    }
}

// Full ascending sort of 4096 floats held as v[64] per thread (A layout).
// Single-wave: no barriers; LDS ordering via compiler lgkmcnt.
__device__ __forceinline__ void sort4096(float* v, float* buf, int t) {
    const int t15 = t & 15;
    const int sAB = (t >> 4) << 8;
    const int qAC = ((t >> 4) << 2) ^ t15;
    const int th  = (t >> 2) & 15;
    const int sCB = (t & 3) << 6;
    const int qCB = (t >> 2) ^ ((t & 3) << 2);

    // merges 2..64: fully in-register (kept unrolled; register indices
    // must be compile-time).
    rev_inreg<1>(v);
    rev_inreg<3>(v);  stages<1, 1>(v);
    rev_inreg<7>(v);  stages<2, 1>(v);
    rev_inreg<15>(v); stages<4, 1>(v);
    rev_inreg<31>(v); stages<8, 1>(v);
    rev_inreg<63>(v); stages<16, 1>(v);

    // merges 128..4096: one shared loop body, runtime masks.
    // mi: 0=m128, 1=m256, 2=m512, 3=m1024, 4=m2048, 5=m4096.
#pragma unroll 1
    for (int mi = 0; mi < 6; ++mi) {
        if (mi <= 1) {
            // shuffle reversal (m128: xm=1 keep t&1; m256: xm=3 keep t&2)
            const int xm = mi ? 3 : 1;
            rev_shfl_rt(v, xm, (t & (mi ? 2 : 1)) != 0);
            if (mi == 1) {
                stage_shfl_rt(v, 2, (t & 2) != 0);
                stage_shfl_rt(v, 1, (t & 1) != 0);
            }
        } else if (mi <= 4) {
            // LDS reversal in B. m512: PM=15 CM=7 KB=4; m1024: PM=15 CM=15
            // KB=8; m2048: PM=31 CM=15 TB=16.
            const int PM = (mi == 4) ? 31 : 15;
            const int CM = (mi == 2) ? 7 : 15;
            const int KB = (mi == 2) ? 4 : (mi == 3) ? 8 : 0;
            const int TB = (mi == 4) ? 16 : 0;
            write_AB(buf, v, sAB, t15);
            read_rev_rt(buf, v, t, t15, PM, CM, KB, TB);
        } else {
            // m4096: reversal in C, j=1024 in C, then C->B.
            write_AC(buf, v, t15, qAC);
            read_rev_C(buf, v, t, th);
            stage1<16>(v);                 // j=1024 (C reg bit 4)
            write_CB(buf, v, sCB, qCB);
            read_own(buf, v, t, t15);      // now B-resident
        }
        // B-resident cleaner chain (uniform scalar conditions):
        // m2048/m4096: j=512; m1024/m2048/m4096: j=256; m512+: j=128,64.
        if (mi >= 4) stage1<32>(v);
        if (mi >= 3) stage1<16>(v);
        if (mi >= 2) { stage1<8>(v); stage1<4>(v); }
        // back to A layout:
        if (mi >= 2) { write_AB(buf, v, sAB, t15); read_own(buf, v, t, t15); }
        // shared tail: j=32..1 in A.
        stages<32, 1>(v);
    }
}

__global__ __launch_bounds__(BLK, 2) void swd_kernel(
    const float* __restrict__ x, const float* __restrict__ y,
    const float* __restrict__ theta, const float* __restrict__ rot,
    float* __restrict__ per_batch) {
    __shared__ float buf2[2][NPTS];

    const int t = threadIdx.x & 63;       // wave lane
    const int w = threadIdx.x >> 6;       // 0: x-wave, 1: y-wave
    const int p = blockIdx.x;
    const int b = blockIdx.y;

    const float t0 = theta[p * 3 + 0], t1 = theta[p * 3 + 1], t2 = theta[p * 3 + 2];
    const float* R = rot + b * 9;
    const float p0 = t0 * R[0] + t1 * R[3] + t2 * R[6];
    const float p1 = t0 * R[1] + t1 * R[4] + t2 * R[7];
    const float p2 = t0 * R[2] + t1 * R[5] + t2 * R[8];

    float* buf = buf2[w];
    const float* src = w ? y : x;

    // Each wave sorts its own array, barrier-free.
    float v[V];
    load_project(src + (size_t)b * NPTS * 3 + (size_t)t * V * 3, v, p0, p1, p2);
    sort4096(v, buf, t);

    const int t15 = t & 15;
    // Wave 1 publishes sorted y in natural A slots; wave 0 then diffs.
    if (w == 1) write_own(buf2[1], v, t, t15);
    __syncthreads();

    if (w == 0) {
        float yv[V];
        read_own(buf2[1], yv, t, t15);
        float s = 0.0f;
#pragma unroll
        for (int r = 0; r < V; ++r) {
            const float d = v[r] - yv[r];
            s += d * d;
        }
        for (int off = 32; off > 0; off >>= 1) s += __shfl_down(s, off, 64);
        if (t == 0) atomicAdd(&per_batch[b], s);
    }
}

__global__ void finalize_kernel(const float* __restrict__ per_batch, float* __restrict__ out) {
    const int t = threadIdx.x;  // 64 threads
    float v = (t < NBATCH) ? sqrtf(per_batch[t] * (1.0f / (float)NPROJ)) : 0.0f;
    for (int off = 32; off > 0; off >>= 1) v += __shfl_down(v, off, 64);
    if (t == 0) out[0] = v * (1.0f / (float)NBATCH);
}

extern "C" void kernel_launch(void* const* d_in, const int* in_sizes, int n_in,
                              void* d_out, int out_size, void* d_ws, size_t ws_size,
                              hipStream_t stream) {
    const float* x = (const float*)d_in[0];
    const float* y = (const float*)d_in[1];
    const float* theta = (const float*)d_in[2];
    const float* rot = (const float*)d_in[3];
    float* per_batch = (float*)d_ws;
    float* out = (float*)d_out;

    hipMemsetAsync(per_batch, 0, NBATCH * sizeof(float), stream);

    dim3 grid(NPROJ, NBATCH);
    swd_kernel<<<grid, BLK, 0, stream>>>(x, y, theta, rot, per_batch);

    finalize_kernel<<<1, 64, 0, stream>>>(per_batch, out);
}